// Round 17
// baseline (28.678 us; speedup 1.0000x reference)
//
#include <hip/hip_runtime.h>
#include <hip/hip_bf16.h>
#include <math.h>

// Problem constants: N=4, E=64, L=512, D=768
#define PN 4
#define PE 64
#define PL 512
#define PD 768
#define PK2 (2 * PD)        // 1536
#define PM (PN * PE)        // 256 rows

#define EG 4                // entities per pool block
#define DCW 256             // d-columns per pool block (float4 per lane)
#define NPOOLB 192          // 8 XCD x 24
#define NCVT2 144           // W-convert blocks (144*1024*8 = PD*PK2)
#define NXCD 8

using bf16x8 = __attribute__((ext_vector_type(8))) short;
using f32x4  = __attribute__((ext_vector_type(4))) float;

static __device__ __forceinline__ unsigned short f2bf(float x) {
    unsigned int u = __float_as_uint(x);
    unsigned int r = (u + 0x7FFFu + ((u >> 16) & 1u)) >> 16;   // RNE
    return (unsigned short)r;
}

// ---------------------------------------------------------------------------
// pool_v11: R16's pool_v10 with the mask machinery deleted. The map values
// ARE {0.0,1.0} floats at wave-uniform addresses -> load m directly (scalar
// broadcast) and use cand = m * v, which is LITERALLY the reference's
// entity_mapping * doc_state element (bit-exact, incl. 0*-x = -0; masked-out
// rows contribute the 0 candidate so max needs no fixup).
// Geometry unchanged from R16: 192 pool + 144 convert blocks, 1024 thr,
// 16 waves x 32-l windows, float4 per lane (16B loads), two-phase 64 KB LDS
// merge, XCD map (xcd -> n = xcd>>1, eg-half = xcd&1; doc slice L2-resident).
// ---------------------------------------------------------------------------
__global__ __launch_bounds__(1024) void pool_v11(
    const float* __restrict__ doc,    // [N][L][D]
    const float* __restrict__ map,    // [N][E][L]
    const float* __restrict__ lens,   // [N][E]
    const float* __restrict__ W,      // [768][1536]
    unsigned short* __restrict__ Pb,  // [256][1536] bf16
    unsigned short* __restrict__ Wb)  // [768][1536] bf16
{
    const int bid = blockIdx.x;
    const int tid = threadIdx.x;

    if (bid >= NPOOLB) {
        // ---- W conversion blocks ----
        const size_t i = ((size_t)(bid - NPOOLB) * 1024 + tid) * 8;
        const float4 a = *reinterpret_cast<const float4*>(W + i);
        const float4 c = *reinterpret_cast<const float4*>(W + i + 4);
        union { unsigned short s[8]; uint4 v; } r;
        r.s[0] = f2bf(a.x); r.s[1] = f2bf(a.y); r.s[2] = f2bf(a.z); r.s[3] = f2bf(a.w);
        r.s[4] = f2bf(c.x); r.s[5] = f2bf(c.y); r.s[6] = f2bf(c.z); r.s[7] = f2bf(c.w);
        *reinterpret_cast<uint4*>(Wb + i) = r.v;
        return;
    }

    __shared__ float lbuf[16][EG][DCW];   // 64 KB, reused max then sum

    const int xcd = bid & (NXCD - 1);
    const int idx = bid >> 3;            // 0..23
    const int n   = xcd >> 1;            // XCD pair owns one n
    const int eg  = (xcd & 1) * 8 + idx / 3;   // 0..15
    const int dc  = idx % 3;             // 0..2
    const int e0  = eg * EG;
    const int d0  = dc * DCW;
    const int w    = tid >> 6;           // 0..15
    const int lane = tid & 63;

    // wave-uniform mask row pointers (scalar loads in the loop)
    const float* mrow0 = map + ((size_t)n * PE + e0 + 0) * PL + w * 32;
    const float* mrow1 = map + ((size_t)n * PE + e0 + 1) * PL + w * 32;
    const float* mrow2 = map + ((size_t)n * PE + e0 + 2) * PL + w * 32;
    const float* mrow3 = map + ((size_t)n * PE + e0 + 3) * PL + w * 32;

    const float* docp = doc + ((size_t)n * PL + w * 32) * PD + d0 + lane * 4;

    float4 mx[EG], sm[EG];
    #pragma unroll
    for (int e = 0; e < EG; ++e) {
        mx[e] = make_float4(-INFINITY, -INFINITY, -INFINITY, -INFINITY);
        sm[e] = make_float4(0.f, 0.f, 0.f, 0.f);
    }

    #pragma unroll 8
    for (int l = 0; l < 32; ++l) {
        const float4 v = *reinterpret_cast<const float4*>(docp + (size_t)l * PD);
        const float m0 = mrow0[l];   // wave-uniform scalar loads
        const float m1 = mrow1[l];
        const float m2 = mrow2[l];
        const float m3 = mrow3[l];
        // cand = m * v == reference entity_mapping*doc_state elem (bit-exact)
        sm[0].x = fmaf(m0, v.x, sm[0].x); sm[0].y = fmaf(m0, v.y, sm[0].y);
        sm[0].z = fmaf(m0, v.z, sm[0].z); sm[0].w = fmaf(m0, v.w, sm[0].w);
        mx[0].x = fmaxf(mx[0].x, m0 * v.x); mx[0].y = fmaxf(mx[0].y, m0 * v.y);
        mx[0].z = fmaxf(mx[0].z, m0 * v.z); mx[0].w = fmaxf(mx[0].w, m0 * v.w);
        sm[1].x = fmaf(m1, v.x, sm[1].x); sm[1].y = fmaf(m1, v.y, sm[1].y);
        sm[1].z = fmaf(m1, v.z, sm[1].z); sm[1].w = fmaf(m1, v.w, sm[1].w);
        mx[1].x = fmaxf(mx[1].x, m1 * v.x); mx[1].y = fmaxf(mx[1].y, m1 * v.y);
        mx[1].z = fmaxf(mx[1].z, m1 * v.z); mx[1].w = fmaxf(mx[1].w, m1 * v.w);
        sm[2].x = fmaf(m2, v.x, sm[2].x); sm[2].y = fmaf(m2, v.y, sm[2].y);
        sm[2].z = fmaf(m2, v.z, sm[2].z); sm[2].w = fmaf(m2, v.w, sm[2].w);
        mx[2].x = fmaxf(mx[2].x, m2 * v.x); mx[2].y = fmaxf(mx[2].y, m2 * v.y);
        mx[2].z = fmaxf(mx[2].z, m2 * v.z); mx[2].w = fmaxf(mx[2].w, m2 * v.w);
        sm[3].x = fmaf(m3, v.x, sm[3].x); sm[3].y = fmaf(m3, v.y, sm[3].y);
        sm[3].z = fmaf(m3, v.z, sm[3].z); sm[3].w = fmaf(m3, v.w, sm[3].w);
        mx[3].x = fmaxf(mx[3].x, m3 * v.x); mx[3].y = fmaxf(mx[3].y, m3 * v.y);
        mx[3].z = fmaxf(mx[3].z, m3 * v.z); mx[3].w = fmaxf(mx[3].w, m3 * v.w);
    }

    // ---- phase 1: max ----
    #pragma unroll
    for (int e = 0; e < EG; ++e)
        *reinterpret_cast<float4*>(&lbuf[w][e][lane * 4]) = mx[e];
    __syncthreads();
    {
        const int e = tid >> 8;          // 0..3
        const int d = tid & 255;         // 0..255
        float m = lbuf[0][e][d];
        #pragma unroll
        for (int ww = 1; ww < 16; ++ww) m = fmaxf(m, lbuf[ww][e][d]);
        const int ne = n * PE + e0 + e;
        Pb[(size_t)ne * PK2 + d0 + d] = f2bf(m);
    }
    __syncthreads();

    // ---- phase 2: sum / mean ----
    #pragma unroll
    for (int e = 0; e < EG; ++e)
        *reinterpret_cast<float4*>(&lbuf[w][e][lane * 4]) = sm[e];
    __syncthreads();
    {
        const int e = tid >> 8;
        const int d = tid & 255;
        float s = lbuf[0][e][d];
        #pragma unroll
        for (int ww = 1; ww < 16; ++ww) s += lbuf[ww][e][d];
        const int ne = n * PE + e0 + e;
        Pb[(size_t)ne * PK2 + PD + d0 + d] = f2bf(s * (1.0f / lens[ne]));
    }
}

// ---------------------------------------------------------------------------
// gemm_ks2x (unchanged from R11/R16): MFMA bf16 16x16x32, K-split 2,
// XCD-aware tile mapping (XCD owns a 6-wide ct stripe; W slice L2-resident).
// ---------------------------------------------------------------------------
__global__ __launch_bounds__(128) void gemm_ks2x(
    const unsigned short* __restrict__ Pb,  // [256][1536] bf16
    const unsigned short* __restrict__ Wb,  // [768][1536] bf16
    const float* __restrict__ b,            // [768]
    float* __restrict__ out)                // [256][768]
{
    __shared__ f32x4 red[64];

    const int w    = threadIdx.x >> 6;
    const int lane = threadIdx.x & 63;
    const int bid  = blockIdx.x;
    const int xcd  = bid & (NXCD - 1);
    const int idx  = bid >> 3;               // 0..95
    const int ct = xcd * 6 + (idx >> 4);     // 0..47
    const int rt = idx & 15;                 // 0..15
    const int r0 = rt * 16, d0 = ct * 16;

    const int fr = lane & 15;
    const int kg = lane >> 4;
    const int kb = w * (PK2 / 2);            // 768-wide K slice per wave

    const unsigned short* pA = Pb + (size_t)(r0 + fr) * PK2 + kb + kg * 8;
    const unsigned short* pB = Wb + (size_t)(d0 + fr) * PK2 + kb + kg * 8;

    f32x4 acc0 = {0.f, 0.f, 0.f, 0.f};
    f32x4 acc1 = {0.f, 0.f, 0.f, 0.f};
    #pragma unroll
    for (int k0 = 0; k0 < PK2 / 2; k0 += 64) {
        const bf16x8 a0 = *reinterpret_cast<const bf16x8*>(pA + k0);
        const bf16x8 b0 = *reinterpret_cast<const bf16x8*>(pB + k0);
        acc0 = __builtin_amdgcn_mfma_f32_16x16x32_bf16(a0, b0, acc0, 0, 0, 0);
        const bf16x8 a1 = *reinterpret_cast<const bf16x8*>(pA + k0 + 32);
        const bf16x8 b1 = *reinterpret_cast<const bf16x8*>(pB + k0 + 32);
        acc1 = __builtin_amdgcn_mfma_f32_16x16x32_bf16(a1, b1, acc1, 0, 0, 0);
    }
    f32x4 acc = acc0 + acc1;

    if (w == 1) red[lane] = acc;
    __syncthreads();
    if (w == 0) {
        acc += red[lane];
        const int c = d0 + fr;
        const float bias = b[c];
        #pragma unroll
        for (int j = 0; j < 4; ++j)
            out[(size_t)(r0 + kg * 4 + j) * PD + c] = acc[j] + bias;
    }
}

// ===========================================================================
// Fallback: fully fused f32 (R1-proven) -- used only if ws is tiny.
// ===========================================================================
__global__ __launch_bounds__(256) void fused_kernel(
    const float* __restrict__ doc, const float* __restrict__ map,
    const float* __restrict__ lens, const float* __restrict__ W,
    const float* __restrict__ b, float* __restrict__ out)
{
    __shared__ float Prow[PK2];
    const int ne = blockIdx.x, n = ne >> 6, t = threadIdx.x;
    const float* docn = doc + (size_t)n * PL * PD;
    const float* mrow = map + (size_t)ne * PL;
    float mx0=-INFINITY, mx1=-INFINITY, mx2=-INFINITY, s0=0.f, s1=0.f, s2=0.f;
    bool has_zero = false;
    for (int l = 0; l < PL; ++l) {
        const float m = mrow[l];
        if (m != 0.0f) {
            const float* dr = docn + (size_t)l * PD;
            const float a = dr[t], c = dr[t+256], e = dr[t+512];
            mx0=fmaxf(mx0,a); s0+=a; mx1=fmaxf(mx1,c); s1+=c; mx2=fmaxf(mx2,e); s2+=e;
        } else has_zero = true;
    }
    if (has_zero) { mx0=fmaxf(mx0,0.f); mx1=fmaxf(mx1,0.f); mx2=fmaxf(mx2,0.f); }
    const float invlen = 1.0f / lens[ne];
    Prow[t]=mx0; Prow[t+256]=mx1; Prow[t+512]=mx2;
    Prow[PD+t]=s0*invlen; Prow[PD+t+256]=s1*invlen; Prow[PD+t+512]=s2*invlen;
    __syncthreads();
    #pragma unroll
    for (int i = 0; i < 3; ++i) {
        const int d = t + i*256;
        const float* wrow = W + (size_t)d * PK2;
        float acc = 0.f;
        for (int k = 0; k < PK2; k += 4) {
            const float4 w = *reinterpret_cast<const float4*>(&wrow[k]);
            acc += Prow[k]*w.x + Prow[k+1]*w.y + Prow[k+2]*w.z + Prow[k+3]*w.w;
        }
        out[(size_t)ne * PD + d] = acc + b[d];
    }
}

extern "C" void kernel_launch(void* const* d_in, const int* in_sizes, int n_in,
                              void* d_out, int out_size, void* d_ws, size_t ws_size,
                              hipStream_t stream) {
    const float* doc  = (const float*)d_in[0];   // (4,512,768)
    const float* map  = (const float*)d_in[1];   // (4,64,512)
    const float* lens = (const float*)d_in[2];   // (4,64)
    const float* W    = (const float*)d_in[3];   // (768,1536)
    const float* b    = (const float*)d_in[4];   // (768,)
    float* out = (float*)d_out;                  // (4,64,768)

    const size_t pb_bytes = (size_t)PM * PK2 * sizeof(unsigned short);   // 768 KiB
    const size_t wb_bytes = (size_t)PD * PK2 * sizeof(unsigned short);   // 2.25 MiB
    const size_t need     = pb_bytes + wb_bytes;                         // 3 MiB

    if (ws_size >= need) {
        unsigned short* Pb = (unsigned short*)d_ws;
        unsigned short* Wb = (unsigned short*)((char*)d_ws + pb_bytes);
        pool_v11<<<dim3(NPOOLB + NCVT2), dim3(1024), 0, stream>>>(
            doc, map, lens, W, Pb, Wb);
        gemm_ks2x<<<dim3((PM / 16) * (PD / 16)), dim3(128), 0, stream>>>(Pb, Wb, b, out);
    } else {
        fused_kernel<<<dim3(PM), dim3(256), 0, stream>>>(doc, map, lens, W, b, out);
    }
}

// Round 18
// 27.318 us; speedup vs baseline: 1.0498x; 1.0498x over previous
//
#include <hip/hip_runtime.h>
#include <hip/hip_bf16.h>
#include <math.h>

// Problem constants: N=4, E=64, L=512, D=768
#define PN 4
#define PE 64
#define PL 512
#define PD 768
#define PK2 (2 * PD)        // 1536
#define PM (PN * PE)        // 256 rows

#define EG 2                // entities per pool block (384 blocks -> full CU fill)
#define DCW 256             // d-columns per pool block (float4 per lane)
#define NPOOLB 384          // 8 XCD x 48
#define NCVT2 144           // W-convert blocks (144*1024*8 = PD*PK2)
#define NXCD 8

using bf16x8 = __attribute__((ext_vector_type(8))) short;
using f32x4  = __attribute__((ext_vector_type(4))) float;

static __device__ __forceinline__ unsigned short f2bf(float x) {
    unsigned int u = __float_as_uint(x);
    unsigned int r = (u + 0x7FFFu + ((u >> 16) & 1u)) >> 16;   // RNE
    return (unsigned short)r;
}

// ---------------------------------------------------------------------------
// pool_v12: R16's proven structure (ballot masks, float4 lanes, 16 waves x
// 32-l windows, all L in-block) with EG 4->2 so the grid is 384 pool blocks:
// every CU gets >=1 pool block (R16's 192 left 64 CUs idle on pool work),
// and 2-block CUs co-reside (32 waves, 128 KB LDS <= 160).
// Masks: 32-bit ballot per (wave, e) -> SGPR (R17 proved per-lane mask loads
// regress: VMEM count is the governing resource).
// cand = mval * v == reference mask*doc elem EXACTLY (0 candidate when
// masked out -> no has_zero fixup).
// Single-phase merge: lmax+lsum both in LDS (64 KB); tid<512 -> max slot,
// tid>=512 -> sum slot.
// XCD map: xcd = bid&7 -> n = xcd>>1, e-half = xcd&1 (doc[n] 1.5 MB
// L2-resident per XCD pair).
// ---------------------------------------------------------------------------
__global__ __launch_bounds__(1024) void pool_v12(
    const float* __restrict__ doc,    // [N][L][D]
    const float* __restrict__ map,    // [N][E][L]
    const float* __restrict__ lens,   // [N][E]
    const float* __restrict__ W,      // [768][1536]
    unsigned short* __restrict__ Pb,  // [256][1536] bf16
    unsigned short* __restrict__ Wb)  // [768][1536] bf16
{
    const int bid = blockIdx.x;
    const int tid = threadIdx.x;

    if (bid >= NPOOLB) {
        // ---- W conversion blocks ----
        const size_t i = ((size_t)(bid - NPOOLB) * 1024 + tid) * 8;
        const float4 a = *reinterpret_cast<const float4*>(W + i);
        const float4 c = *reinterpret_cast<const float4*>(W + i + 4);
        union { unsigned short s[8]; uint4 v; } r;
        r.s[0] = f2bf(a.x); r.s[1] = f2bf(a.y); r.s[2] = f2bf(a.z); r.s[3] = f2bf(a.w);
        r.s[4] = f2bf(c.x); r.s[5] = f2bf(c.y); r.s[6] = f2bf(c.z); r.s[7] = f2bf(c.w);
        *reinterpret_cast<uint4*>(Wb + i) = r.v;
        return;
    }

    __shared__ float lmax[16][EG][DCW];   // 32 KB
    __shared__ float lsum[16][EG][DCW];   // 32 KB

    const int xcd = bid & (NXCD - 1);
    const int idx = bid >> 3;            // 0..47
    const int n   = xcd >> 1;            // XCD pair owns one n
    const int eg  = (xcd & 1) * 16 + idx / 3;   // 0..31
    const int dc  = idx % 3;             // 0..2
    const int e0  = eg * EG;
    const int d0  = dc * DCW;
    const int w    = tid >> 6;           // 0..15
    const int lane = tid & 63;

    // per-wave 32-bit masks for its 32-l window (wave-uniform SGPR)
    unsigned int mk[EG];
    #pragma unroll
    for (int e = 0; e < EG; ++e) {
        const float m = map[((size_t)n * PE + e0 + e) * PL + w * 32 + (lane & 31)];
        mk[e] = (unsigned int)__ballot(m != 0.0f);
    }

    const float* docp = doc + ((size_t)n * PL + w * 32) * PD + d0 + lane * 4;

    float4 mx[EG], sm[EG];
    #pragma unroll
    for (int e = 0; e < EG; ++e) {
        mx[e] = make_float4(-INFINITY, -INFINITY, -INFINITY, -INFINITY);
        sm[e] = make_float4(0.f, 0.f, 0.f, 0.f);
    }

    #pragma unroll 8
    for (int l = 0; l < 32; ++l) {
        const float4 v = *reinterpret_cast<const float4*>(docp + (size_t)l * PD);
        #pragma unroll
        for (int e = 0; e < EG; ++e) {
            const float mval = ((mk[e] >> l) & 1u) ? 1.0f : 0.0f;  // s_cselect
            const float cx = mval * v.x, cy = mval * v.y;          // == ref elem
            const float cz = mval * v.z, cw = mval * v.w;
            sm[e].x += cx; sm[e].y += cy; sm[e].z += cz; sm[e].w += cw;
            mx[e].x = fmaxf(mx[e].x, cx); mx[e].y = fmaxf(mx[e].y, cy);
            mx[e].z = fmaxf(mx[e].z, cz); mx[e].w = fmaxf(mx[e].w, cw);
        }
    }

    #pragma unroll
    for (int e = 0; e < EG; ++e) {
        *reinterpret_cast<float4*>(&lmax[w][e][lane * 4]) = mx[e];
        *reinterpret_cast<float4*>(&lsum[w][e][lane * 4]) = sm[e];
    }
    __syncthreads();

    // single-phase merge: 512 (e,d) slots; tid<512 -> max, tid>=512 -> sum
    const int slot = tid & 511;
    const int e = slot >> 8;             // 0..1
    const int d = slot & 255;            // 0..255
    const int ne = n * PE + e0 + e;
    if (tid < 512) {
        float m = lmax[0][e][d];
        #pragma unroll
        for (int ww = 1; ww < 16; ++ww) m = fmaxf(m, lmax[ww][e][d]);
        Pb[(size_t)ne * PK2 + d0 + d] = f2bf(m);
    } else {
        float s = lsum[0][e][d];
        #pragma unroll
        for (int ww = 1; ww < 16; ++ww) s += lsum[ww][e][d];
        Pb[(size_t)ne * PK2 + PD + d0 + d] = f2bf(s * (1.0f / lens[ne]));
    }
}

// ---------------------------------------------------------------------------
// gemm_ks2x (unchanged from R11/R16): MFMA bf16 16x16x32, K-split 2,
// XCD-aware tile mapping (XCD owns a 6-wide ct stripe; W slice L2-resident).
// ---------------------------------------------------------------------------
__global__ __launch_bounds__(128) void gemm_ks2x(
    const unsigned short* __restrict__ Pb,  // [256][1536] bf16
    const unsigned short* __restrict__ Wb,  // [768][1536] bf16
    const float* __restrict__ b,            // [768]
    float* __restrict__ out)                // [256][768]
{
    __shared__ f32x4 red[64];

    const int w    = threadIdx.x >> 6;
    const int lane = threadIdx.x & 63;
    const int bid  = blockIdx.x;
    const int xcd  = bid & (NXCD - 1);
    const int idx  = bid >> 3;               // 0..95
    const int ct = xcd * 6 + (idx >> 4);     // 0..47
    const int rt = idx & 15;                 // 0..15
    const int r0 = rt * 16, d0 = ct * 16;

    const int fr = lane & 15;
    const int kg = lane >> 4;
    const int kb = w * (PK2 / 2);            // 768-wide K slice per wave

    const unsigned short* pA = Pb + (size_t)(r0 + fr) * PK2 + kb + kg * 8;
    const unsigned short* pB = Wb + (size_t)(d0 + fr) * PK2 + kb + kg * 8;

    f32x4 acc0 = {0.f, 0.f, 0.f, 0.f};
    f32x4 acc1 = {0.f, 0.f, 0.f, 0.f};
    #pragma unroll
    for (int k0 = 0; k0 < PK2 / 2; k0 += 64) {
        const bf16x8 a0 = *reinterpret_cast<const bf16x8*>(pA + k0);
        const bf16x8 b0 = *reinterpret_cast<const bf16x8*>(pB + k0);
        acc0 = __builtin_amdgcn_mfma_f32_16x16x32_bf16(a0, b0, acc0, 0, 0, 0);
        const bf16x8 a1 = *reinterpret_cast<const bf16x8*>(pA + k0 + 32);
        const bf16x8 b1 = *reinterpret_cast<const bf16x8*>(pB + k0 + 32);
        acc1 = __builtin_amdgcn_mfma_f32_16x16x32_bf16(a1, b1, acc1, 0, 0, 0);
    }
    f32x4 acc = acc0 + acc1;

    if (w == 1) red[lane] = acc;
    __syncthreads();
    if (w == 0) {
        acc += red[lane];
        const int c = d0 + fr;
        const float bias = b[c];
        #pragma unroll
        for (int j = 0; j < 4; ++j)
            out[(size_t)(r0 + kg * 4 + j) * PD + c] = acc[j] + bias;
    }
}

// ===========================================================================
// Fallback: fully fused f32 (R1-proven) -- used only if ws is tiny.
// ===========================================================================
__global__ __launch_bounds__(256) void fused_kernel(
    const float* __restrict__ doc, const float* __restrict__ map,
    const float* __restrict__ lens, const float* __restrict__ W,
    const float* __restrict__ b, float* __restrict__ out)
{
    __shared__ float Prow[PK2];
    const int ne = blockIdx.x, n = ne >> 6, t = threadIdx.x;
    const float* docn = doc + (size_t)n * PL * PD;
    const float* mrow = map + (size_t)ne * PL;
    float mx0=-INFINITY, mx1=-INFINITY, mx2=-INFINITY, s0=0.f, s1=0.f, s2=0.f;
    bool has_zero = false;
    for (int l = 0; l < PL; ++l) {
        const float m = mrow[l];
        if (m != 0.0f) {
            const float* dr = docn + (size_t)l * PD;
            const float a = dr[t], c = dr[t+256], e = dr[t+512];
            mx0=fmaxf(mx0,a); s0+=a; mx1=fmaxf(mx1,c); s1+=c; mx2=fmaxf(mx2,e); s2+=e;
        } else has_zero = true;
    }
    if (has_zero) { mx0=fmaxf(mx0,0.f); mx1=fmaxf(mx1,0.f); mx2=fmaxf(mx2,0.f); }
    const float invlen = 1.0f / lens[ne];
    Prow[t]=mx0; Prow[t+256]=mx1; Prow[t+512]=mx2;
    Prow[PD+t]=s0*invlen; Prow[PD+t+256]=s1*invlen; Prow[PD+t+512]=s2*invlen;
    __syncthreads();
    #pragma unroll
    for (int i = 0; i < 3; ++i) {
        const int d = t + i*256;
        const float* wrow = W + (size_t)d * PK2;
        float acc = 0.f;
        for (int k = 0; k < PK2; k += 4) {
            const float4 w = *reinterpret_cast<const float4*>(&wrow[k]);
            acc += Prow[k]*w.x + Prow[k+1]*w.y + Prow[k+2]*w.z + Prow[k+3]*w.w;
        }
        out[(size_t)ne * PD + d] = acc + b[d];
    }
}

extern "C" void kernel_launch(void* const* d_in, const int* in_sizes, int n_in,
                              void* d_out, int out_size, void* d_ws, size_t ws_size,
                              hipStream_t stream) {
    const float* doc  = (const float*)d_in[0];   // (4,512,768)
    const float* map  = (const float*)d_in[1];   // (4,64,512)
    const float* lens = (const float*)d_in[2];   // (4,64)
    const float* W    = (const float*)d_in[3];   // (768,1536)
    const float* b    = (const float*)d_in[4];   // (768,)
    float* out = (float*)d_out;                  // (4,64,768)

    const size_t pb_bytes = (size_t)PM * PK2 * sizeof(unsigned short);   // 768 KiB
    const size_t wb_bytes = (size_t)PD * PK2 * sizeof(unsigned short);   // 2.25 MiB
    const size_t need     = pb_bytes + wb_bytes;                         // 3 MiB

    if (ws_size >= need) {
        unsigned short* Pb = (unsigned short*)d_ws;
        unsigned short* Wb = (unsigned short*)((char*)d_ws + pb_bytes);
        pool_v12<<<dim3(NPOOLB + NCVT2), dim3(1024), 0, stream>>>(
            doc, map, lens, W, Pb, Wb);
        gemm_ks2x<<<dim3((PM / 16) * (PD / 16)), dim3(128), 0, stream>>>(Pb, Wb, b, out);
    } else {
        fused_kernel<<<dim3(PM), dim3(256), 0, stream>>>(doc, map, lens, W, b, out);
    }
}

// Round 19
// 26.704 us; speedup vs baseline: 1.0739x; 1.0230x over previous
//
#include <hip/hip_runtime.h>
#include <hip/hip_bf16.h>
#include <math.h>

// Problem constants: N=4, E=64, L=512, D=768
#define PN 4
#define PE 64
#define PL 512
#define PD 768
#define PK2 (2 * PD)        // 1536
#define PM (PN * PE)        // 256 rows

#define EG 4                // entities per pool block
#define DCW 256             // d-columns per pool block (float4 per lane)
#define NPOOLB 192          // 8 XCD x 24
#define NCVT2 144           // W-convert blocks (144*1024*8 = PD*PK2)
#define NXCD 8

using bf16x8 = __attribute__((ext_vector_type(8))) short;
using f32x4  = __attribute__((ext_vector_type(4))) float;

static __device__ __forceinline__ unsigned short f2bf(float x) {
    unsigned int u = __float_as_uint(x);
    unsigned int r = (u + 0x7FFFu + ((u >> 16) & 1u)) >> 16;   // RNE
    return (unsigned short)r;
}

// ---------------------------------------------------------------------------
// pool_v10 (R16 champion, 26.6 us): WIDE loads. 192 pool + 144 W-convert
// blocks, 1024 threads. Pool block = (n, e-group of 4, d-chunk of 256).
// 16 waves; wave w owns l in [w*32, w*32+32). Lane owns FOUR d columns
// (one float4 load/iter: 16 B/lane -- 4x fewer VMEM instructions than
// scalar at identical traffic/VALU; proven -2us vs scalar, R15->R16).
// Masks: 32-bit ballot per (wave, e) -> SGPR (per-lane mask loads proven
// to regress, R17). cand = mval * v == reference mask*doc elem EXACTLY
// (masked-out -> 0 candidate, so max needs no fixup).
// Merge: one 64 KB LDS buffer, two phases (max, then sum) -> 64 KB keeps
// pool+convert co-residency (128 KB single-phase variant would not).
// XCD map: xcd = bid&7 -> n = xcd>>1, eg-half = xcd&1 (doc slice
// L2-resident per XCD; proven -2us, R10->R11).
// ---------------------------------------------------------------------------
__global__ __launch_bounds__(1024) void pool_v10(
    const float* __restrict__ doc,    // [N][L][D]
    const float* __restrict__ map,    // [N][E][L]
    const float* __restrict__ lens,   // [N][E]
    const float* __restrict__ W,      // [768][1536]
    unsigned short* __restrict__ Pb,  // [256][1536] bf16
    unsigned short* __restrict__ Wb)  // [768][1536] bf16
{
    const int bid = blockIdx.x;
    const int tid = threadIdx.x;

    if (bid >= NPOOLB) {
        // ---- W conversion blocks ----
        const size_t i = ((size_t)(bid - NPOOLB) * 1024 + tid) * 8;
        const float4 a = *reinterpret_cast<const float4*>(W + i);
        const float4 c = *reinterpret_cast<const float4*>(W + i + 4);
        union { unsigned short s[8]; uint4 v; } r;
        r.s[0] = f2bf(a.x); r.s[1] = f2bf(a.y); r.s[2] = f2bf(a.z); r.s[3] = f2bf(a.w);
        r.s[4] = f2bf(c.x); r.s[5] = f2bf(c.y); r.s[6] = f2bf(c.z); r.s[7] = f2bf(c.w);
        *reinterpret_cast<uint4*>(Wb + i) = r.v;
        return;
    }

    __shared__ float lbuf[16][EG][DCW];   // 64 KB, reused max then sum

    const int xcd = bid & (NXCD - 1);
    const int idx = bid >> 3;            // 0..23
    const int n   = xcd >> 1;            // XCD pair owns one n
    const int eg  = (xcd & 1) * 8 + idx / 3;   // 0..15
    const int dc  = idx % 3;             // 0..2
    const int e0  = eg * EG;
    const int d0  = dc * DCW;
    const int w    = tid >> 6;           // 0..15
    const int lane = tid & 63;

    // per-wave 32-bit masks for its 32-l window (wave-uniform SGPR)
    unsigned int mk[EG];
    #pragma unroll
    for (int e = 0; e < EG; ++e) {
        const float m = map[((size_t)n * PE + e0 + e) * PL + w * 32 + (lane & 31)];
        mk[e] = (unsigned int)__ballot(m != 0.0f);
    }

    const float* docp = doc + ((size_t)n * PL + w * 32) * PD + d0 + lane * 4;

    float4 mx[EG], sm[EG];
    #pragma unroll
    for (int e = 0; e < EG; ++e) {
        mx[e] = make_float4(-INFINITY, -INFINITY, -INFINITY, -INFINITY);
        sm[e] = make_float4(0.f, 0.f, 0.f, 0.f);
    }

    #pragma unroll 8
    for (int l = 0; l < 32; ++l) {
        const float4 v = *reinterpret_cast<const float4*>(docp + (size_t)l * PD);
        #pragma unroll
        for (int e = 0; e < EG; ++e) {
            const float mval = ((mk[e] >> l) & 1u) ? 1.0f : 0.0f;  // s_cselect
            const float cx = mval * v.x, cy = mval * v.y;          // == ref elem
            const float cz = mval * v.z, cw = mval * v.w;
            sm[e].x += cx; sm[e].y += cy; sm[e].z += cz; sm[e].w += cw;
            mx[e].x = fmaxf(mx[e].x, cx); mx[e].y = fmaxf(mx[e].y, cy);
            mx[e].z = fmaxf(mx[e].z, cz); mx[e].w = fmaxf(mx[e].w, cw);
        }
    }

    // ---- phase 1: max ----
    #pragma unroll
    for (int e = 0; e < EG; ++e)
        *reinterpret_cast<float4*>(&lbuf[w][e][lane * 4]) = mx[e];
    __syncthreads();
    {
        const int e = tid >> 8;          // 0..3
        const int d = tid & 255;         // 0..255
        float m = lbuf[0][e][d];
        #pragma unroll
        for (int ww = 1; ww < 16; ++ww) m = fmaxf(m, lbuf[ww][e][d]);
        const int ne = n * PE + e0 + e;
        Pb[(size_t)ne * PK2 + d0 + d] = f2bf(m);
    }
    __syncthreads();

    // ---- phase 2: sum / mean ----
    #pragma unroll
    for (int e = 0; e < EG; ++e)
        *reinterpret_cast<float4*>(&lbuf[w][e][lane * 4]) = sm[e];
    __syncthreads();
    {
        const int e = tid >> 8;
        const int d = tid & 255;
        float s = lbuf[0][e][d];
        #pragma unroll
        for (int ww = 1; ww < 16; ++ww) s += lbuf[ww][e][d];
        const int ne = n * PE + e0 + e;
        Pb[(size_t)ne * PK2 + PD + d0 + d] = f2bf(s * (1.0f / lens[ne]));
    }
}

// ---------------------------------------------------------------------------
// gemm_ks2x (unchanged from R11/R16): MFMA bf16 16x16x32, K-split 2,
// XCD-aware tile mapping (XCD owns a 6-wide ct stripe; W slice L2-resident).
// ---------------------------------------------------------------------------
__global__ __launch_bounds__(128) void gemm_ks2x(
    const unsigned short* __restrict__ Pb,  // [256][1536] bf16
    const unsigned short* __restrict__ Wb,  // [768][1536] bf16
    const float* __restrict__ b,            // [768]
    float* __restrict__ out)                // [256][768]
{
    __shared__ f32x4 red[64];

    const int w    = threadIdx.x >> 6;
    const int lane = threadIdx.x & 63;
    const int bid  = blockIdx.x;
    const int xcd  = bid & (NXCD - 1);
    const int idx  = bid >> 3;               // 0..95
    const int ct = xcd * 6 + (idx >> 4);     // 0..47
    const int rt = idx & 15;                 // 0..15
    const int r0 = rt * 16, d0 = ct * 16;

    const int fr = lane & 15;
    const int kg = lane >> 4;
    const int kb = w * (PK2 / 2);            // 768-wide K slice per wave

    const unsigned short* pA = Pb + (size_t)(r0 + fr) * PK2 + kb + kg * 8;
    const unsigned short* pB = Wb + (size_t)(d0 + fr) * PK2 + kb + kg * 8;

    f32x4 acc0 = {0.f, 0.f, 0.f, 0.f};
    f32x4 acc1 = {0.f, 0.f, 0.f, 0.f};
    #pragma unroll
    for (int k0 = 0; k0 < PK2 / 2; k0 += 64) {
        const bf16x8 a0 = *reinterpret_cast<const bf16x8*>(pA + k0);
        const bf16x8 b0 = *reinterpret_cast<const bf16x8*>(pB + k0);
        acc0 = __builtin_amdgcn_mfma_f32_16x16x32_bf16(a0, b0, acc0, 0, 0, 0);
        const bf16x8 a1 = *reinterpret_cast<const bf16x8*>(pA + k0 + 32);
        const bf16x8 b1 = *reinterpret_cast<const bf16x8*>(pB + k0 + 32);
        acc1 = __builtin_amdgcn_mfma_f32_16x16x32_bf16(a1, b1, acc1, 0, 0, 0);
    }
    f32x4 acc = acc0 + acc1;

    if (w == 1) red[lane] = acc;
    __syncthreads();
    if (w == 0) {
        acc += red[lane];
        const int c = d0 + fr;
        const float bias = b[c];
        #pragma unroll
        for (int j = 0; j < 4; ++j)
            out[(size_t)(r0 + kg * 4 + j) * PD + c] = acc[j] + bias;
    }
}

// ===========================================================================
// Fallback: fully fused f32 (R1-proven) -- used only if ws is tiny.
// ===========================================================================
__global__ __launch_bounds__(256) void fused_kernel(
    const float* __restrict__ doc, const float* __restrict__ map,
    const float* __restrict__ lens, const float* __restrict__ W,
    const float* __restrict__ b, float* __restrict__ out)
{
    __shared__ float Prow[PK2];
    const int ne = blockIdx.x, n = ne >> 6, t = threadIdx.x;
    const float* docn = doc + (size_t)n * PL * PD;
    const float* mrow = map + (size_t)ne * PL;
    float mx0=-INFINITY, mx1=-INFINITY, mx2=-INFINITY, s0=0.f, s1=0.f, s2=0.f;
    bool has_zero = false;
    for (int l = 0; l < PL; ++l) {
        const float m = mrow[l];
        if (m != 0.0f) {
            const float* dr = docn + (size_t)l * PD;
            const float a = dr[t], c = dr[t+256], e = dr[t+512];
            mx0=fmaxf(mx0,a); s0+=a; mx1=fmaxf(mx1,c); s1+=c; mx2=fmaxf(mx2,e); s2+=e;
        } else has_zero = true;
    }
    if (has_zero) { mx0=fmaxf(mx0,0.f); mx1=fmaxf(mx1,0.f); mx2=fmaxf(mx2,0.f); }
    const float invlen = 1.0f / lens[ne];
    Prow[t]=mx0; Prow[t+256]=mx1; Prow[t+512]=mx2;
    Prow[PD+t]=s0*invlen; Prow[PD+t+256]=s1*invlen; Prow[PD+t+512]=s2*invlen;
    __syncthreads();
    #pragma unroll
    for (int i = 0; i < 3; ++i) {
        const int d = t + i*256;
        const float* wrow = W + (size_t)d * PK2;
        float acc = 0.f;
        for (int k = 0; k < PK2; k += 4) {
            const float4 w = *reinterpret_cast<const float4*>(&wrow[k]);
            acc += Prow[k]*w.x + Prow[k+1]*w.y + Prow[k+2]*w.z + Prow[k+3]*w.w;
        }
        out[(size_t)ne * PD + d] = acc + b[d];
    }
}

extern "C" void kernel_launch(void* const* d_in, const int* in_sizes, int n_in,
                              void* d_out, int out_size, void* d_ws, size_t ws_size,
                              hipStream_t stream) {
    const float* doc  = (const float*)d_in[0];   // (4,512,768)
    const float* map  = (const float*)d_in[1];   // (4,64,512)
    const float* lens = (const float*)d_in[2];   // (4,64)
    const float* W    = (const float*)d_in[3];   // (768,1536)
    const float* b    = (const float*)d_in[4];   // (768,)
    float* out = (float*)d_out;                  // (4,64,768)

    const size_t pb_bytes = (size_t)PM * PK2 * sizeof(unsigned short);   // 768 KiB
    const size_t wb_bytes = (size_t)PD * PK2 * sizeof(unsigned short);   // 2.25 MiB
    const size_t need     = pb_bytes + wb_bytes;                         // 3 MiB

    if (ws_size >= need) {
        unsigned short* Pb = (unsigned short*)d_ws;
        unsigned short* Wb = (unsigned short*)((char*)d_ws + pb_bytes);
        pool_v10<<<dim3(NPOOLB + NCVT2), dim3(1024), 0, stream>>>(
            doc, map, lens, W, Pb, Wb);
        gemm_ks2x<<<dim3((PM / 16) * (PD / 16)), dim3(128), 0, stream>>>(Pb, Wb, b, out);
    } else {
        fused_kernel<<<dim3(PM), dim3(256), 0, stream>>>(doc, map, lens, W, b, out);
    }
}